// Round 1
// baseline (4030.743 us; speedup 1.0000x reference)
//
#include <hip/hip_runtime.h>
#include <stdint.h>
#include <stddef.h>

#define C_DIM 1024
#define T_DIM 1024
#define B_DIM 4
#define L_DIM 8
#define V_DIM 32000
#define HS 64
#define NHEAD 16
#define NROWS (B_DIM * T_DIM)   // 4096

typedef __bf16 bf16_t;
typedef __attribute__((ext_vector_type(8))) __bf16 bf16x8;
typedef __attribute__((ext_vector_type(4))) __bf16 bf16x4;
typedef __attribute__((ext_vector_type(4))) float f32x4;

static __device__ __forceinline__ f32x4 mfma16(bf16x8 a, bf16x8 b, f32x4 c) {
    return __builtin_amdgcn_mfma_f32_16x16x32_bf16(a, b, c, 0, 0, 0);
}

// ---------------------------------------------------------------------------
// Embedding: h[row][c] = tok_emb[x[row]][c] + pos_emb[row % T][c]   (fp32)
// ---------------------------------------------------------------------------
__global__ __launch_bounds__(256) void embed_kernel(
    const int* __restrict__ x, const float* __restrict__ tok,
    const float* __restrict__ pos, float* __restrict__ h) {
    int idx = blockIdx.x * 256 + threadIdx.x;   // one float4 per thread
    int row = idx >> 8;                         // 256 float4 per row
    int c4  = (idx & 255) * 4;
    int t   = row & (T_DIM - 1);
    int tk  = x[row];
    float4 a = *(const float4*)(tok + (size_t)tk * C_DIM + c4);
    float4 p = *(const float4*)(pos + (size_t)t * C_DIM + c4);
    float4 r;
    r.x = a.x + p.x; r.y = a.y + p.y; r.z = a.z + p.z; r.w = a.w + p.w;
    *(float4*)(h + (size_t)row * C_DIM + c4) = r;
}

// ---------------------------------------------------------------------------
// LayerNorm fp32 -> bf16.  One wave per row (C=1024 -> 16 floats/lane).
// ---------------------------------------------------------------------------
__global__ __launch_bounds__(256) void ln_kernel(
    const float* __restrict__ x, const float* __restrict__ gam,
    const float* __restrict__ bet, bf16_t* __restrict__ out) {
    int wave = threadIdx.x >> 6, lane = threadIdx.x & 63;
    int row  = blockIdx.x * 4 + wave;
    const float* xr = x + (size_t)row * C_DIM;
    float4 v[4];
    float s = 0.f, sq = 0.f;
#pragma unroll
    for (int i = 0; i < 4; ++i) {
        v[i] = *(const float4*)(xr + i * 256 + lane * 4);
        s  += v[i].x + v[i].y + v[i].z + v[i].w;
        sq += v[i].x * v[i].x + v[i].y * v[i].y + v[i].z * v[i].z + v[i].w * v[i].w;
    }
#pragma unroll
    for (int m = 1; m < 64; m <<= 1) {
        s  += __shfl_xor(s, m);
        sq += __shfl_xor(sq, m);
    }
    float mu  = s * (1.f / 1024.f);
    float var = sq * (1.f / 1024.f) - mu * mu;
    float rs  = rsqrtf(var + 1e-5f);
    bf16_t* orow = out + (size_t)row * C_DIM;
#pragma unroll
    for (int i = 0; i < 4; ++i) {
        int c = i * 256 + lane * 4;
        float4 g4 = *(const float4*)(gam + c);
        float4 b4 = *(const float4*)(bet + c);
        bf16x4 o;
        o[0] = (bf16_t)((v[i].x - mu) * rs * g4.x + b4.x);
        o[1] = (bf16_t)((v[i].y - mu) * rs * g4.y + b4.y);
        o[2] = (bf16_t)((v[i].z - mu) * rs * g4.z + b4.z);
        o[3] = (bf16_t)((v[i].w - mu) * rs * g4.w + b4.w);
        *(bf16x4*)(orow + c) = o;
    }
}

// ---------------------------------------------------------------------------
// GEMM: C[M,N] (mode) = A_bf16[M,K] @ B_f32[K,N] (+bias)
// MODE 0: store bf16   1: store bf16 relu(+bias)   2: f32 += (+bias)   3: store f32
// 128x128 tile, BK=32, 256 threads (2x2 waves of 64x64), double-buffered LDS.
// B is converted fp32->bf16 during staging and stored TRANSPOSED ([N][K]).
// ---------------------------------------------------------------------------
template <int MODE>
__global__ __launch_bounds__(256) void gemm_kernel(
    const bf16_t* __restrict__ A, const float* __restrict__ Bw,
    const float* __restrict__ bias, void* __restrict__ Cout,
    int M, int N, int K) {
    __shared__ bf16_t Asm[2][128][40];   // [m][k] pad 40
    __shared__ bf16_t Bsm[2][128][40];   // [n][k] pad 40 (transposed)

    const int tid  = threadIdx.x;
    const int MT   = M >> 7;
    const int mt   = blockIdx.x % MT, nt = blockIdx.x / MT;
    const int mbase = mt << 7, nbase = nt << 7;
    const int wave = tid >> 6, lane = tid & 63;
    const int lr = lane & 15, lg = lane >> 4;
    const int wm = wave >> 1, wn = wave & 1;
    const int NK = K >> 5;

    // A staging: thread -> (row=tid>>1, 16 bf16 at k=(tid&1)*16)
    const int arow = tid >> 1, acol = (tid & 1) << 4;
    const bf16_t* aptr = A + (size_t)(mbase + arow) * K + acol;
    // B staging: thread -> n=tid&127, kq in {tid>>7 + 2s}
    const int bn  = tid & 127;
    const int bkq = tid >> 7;
    const float* bptr = Bw + (size_t)nbase + bn;

    uint4 a0, a1;
    float br[4][4];

    // prologue: stage k-tile 0 into buf 0
    a0 = *(const uint4*)(aptr);
    a1 = *(const uint4*)(aptr + 8);
#pragma unroll
    for (int s = 0; s < 4; ++s) {
        int kq = bkq + 2 * s;
#pragma unroll
        for (int j = 0; j < 4; ++j)
            br[s][j] = bptr[(size_t)(kq * 4 + j) * N];
    }
    *(uint4*)&Asm[0][arow][acol]     = a0;
    *(uint4*)&Asm[0][arow][acol + 8] = a1;
#pragma unroll
    for (int s = 0; s < 4; ++s) {
        bf16x4 t;
        t[0] = (bf16_t)br[s][0]; t[1] = (bf16_t)br[s][1];
        t[2] = (bf16_t)br[s][2]; t[3] = (bf16_t)br[s][3];
        *(bf16x4*)&Bsm[0][bn][(bkq + 2 * s) * 4] = t;
    }
    __syncthreads();

    f32x4 acc[4][4] = {};

    for (int kt = 0; kt < NK; ++kt) {
        const int rb = kt & 1;
        // issue next-tile global loads early
        if (kt + 1 < NK) {
            const bf16_t* ap = aptr + (size_t)(kt + 1) * 32;
            a0 = *(const uint4*)(ap);
            a1 = *(const uint4*)(ap + 8);
            const float* bp = bptr + (size_t)(kt + 1) * 32 * N;
#pragma unroll
            for (int s = 0; s < 4; ++s) {
                int kq = bkq + 2 * s;
#pragma unroll
                for (int j = 0; j < 4; ++j)
                    br[s][j] = bp[(size_t)(kq * 4 + j) * N];
            }
        }
        // compute on buf rb
        bf16x8 af[4], bfr[4];
#pragma unroll
        for (int i = 0; i < 4; ++i)
            af[i] = *(const bf16x8*)&Asm[rb][wm * 64 + i * 16 + lr][lg * 8];
#pragma unroll
        for (int j = 0; j < 4; ++j)
            bfr[j] = *(const bf16x8*)&Bsm[rb][wn * 64 + j * 16 + lr][lg * 8];
#pragma unroll
        for (int i = 0; i < 4; ++i)
#pragma unroll
            for (int j = 0; j < 4; ++j)
                acc[i][j] = mfma16(af[i], bfr[j], acc[i][j]);
        // write next tile into the other buffer
        if (kt + 1 < NK) {
            const int wb = rb ^ 1;
            *(uint4*)&Asm[wb][arow][acol]     = a0;
            *(uint4*)&Asm[wb][arow][acol + 8] = a1;
#pragma unroll
            for (int s = 0; s < 4; ++s) {
                bf16x4 t;
                t[0] = (bf16_t)br[s][0]; t[1] = (bf16_t)br[s][1];
                t[2] = (bf16_t)br[s][2]; t[3] = (bf16_t)br[s][3];
                *(bf16x4*)&Bsm[wb][bn][(bkq + 2 * s) * 4] = t;
            }
        }
        __syncthreads();
    }

    // epilogue
    float bj[4];
#pragma unroll
    for (int j = 0; j < 4; ++j)
        bj[j] = bias ? bias[nbase + wn * 64 + j * 16 + lr] : 0.0f;
#pragma unroll
    for (int i = 0; i < 4; ++i) {
#pragma unroll
        for (int j = 0; j < 4; ++j) {
            int col = nbase + wn * 64 + j * 16 + lr;
#pragma unroll
            for (int e = 0; e < 4; ++e) {
                int row = mbase + wm * 64 + i * 16 + lg * 4 + e;
                float val = acc[i][j][e] + bj[j];
                size_t off = (size_t)row * N + col;
                if (MODE == 0) {
                    ((bf16_t*)Cout)[off] = (bf16_t)val;
                } else if (MODE == 1) {
                    ((bf16_t*)Cout)[off] = (bf16_t)fmaxf(val, 0.0f);
                } else if (MODE == 2) {
                    ((float*)Cout)[off] += val;
                } else {
                    ((float*)Cout)[off] = val;
                }
            }
        }
    }
}

// ---------------------------------------------------------------------------
// Flash attention (causal).  Block = (b, h, 64-row q tile), 4 waves x 16 rows.
// hs = 64, key tiles of 32.  q,k,v,o layout: [B,T,H*hs] bf16.
// ---------------------------------------------------------------------------
__global__ __launch_bounds__(256) void attn_kernel(
    const bf16_t* __restrict__ Qb, const bf16_t* __restrict__ Kb,
    const bf16_t* __restrict__ Vb, bf16_t* __restrict__ Ob) {
    __shared__ bf16_t Ksm[32][72];       // [key][d]   pad 72
    __shared__ bf16_t Vsm[64][40];       // [d][key]   transposed, pad 40
    __shared__ bf16_t Psm[4][16][40];    // per-wave P  [q][key] pad 40

    const int tid  = threadIdx.x;
    const int bid  = blockIdx.x;
    const int qt   = bid & 15;
    const int hh   = (bid >> 4) & 15;
    const int bb   = bid >> 8;
    const int wave = tid >> 6, lane = tid & 63;
    const int lr = lane & 15, lg = lane >> 4;
    const int qbase = qt * 64 + wave * 16;
    const size_t base = ((size_t)bb * T_DIM) * C_DIM + hh * HS;

    // Q fragments (held in registers for the whole kernel)
    const bf16_t* qrow = Qb + base + (size_t)(qbase + lr) * C_DIM;
    bf16x8 qf0 = *(const bf16x8*)(qrow + lg * 8);
    bf16x8 qf1 = *(const bf16x8*)(qrow + 32 + lg * 8);

    f32x4 o[4] = {};
    float m_run[4], l_run[4];
#pragma unroll
    for (int e = 0; e < 4; ++e) { m_run[e] = -1e30f; l_run[e] = 0.f; }

    const int skey = tid >> 3, sch = tid & 7;   // staging: 32 keys x 8 chunks
    const bf16_t* kst = Kb + base + (size_t)skey * C_DIM + sch * 8;
    const bf16_t* vst = Vb + base + (size_t)skey * C_DIM + sch * 8;

    const int nkt = 2 * qt + 2;
    for (int kt = 0; kt < nkt; ++kt) {
        __syncthreads();   // previous tile fully consumed
        uint4 kv = *(const uint4*)(kst + (size_t)kt * 32 * C_DIM);
        uint4 vv = *(const uint4*)(vst + (size_t)kt * 32 * C_DIM);
        *(uint4*)&Ksm[skey][sch * 8] = kv;
        const bf16_t* ve = (const bf16_t*)&vv;
#pragma unroll
        for (int j = 0; j < 8; ++j) Vsm[sch * 8 + j][skey] = ve[j];
        __syncthreads();

        // S = Q @ K^T  (two 16-key subtiles)
        f32x4 s[2];
#pragma unroll
        for (int kk = 0; kk < 2; ++kk) {
            bf16x8 k0 = *(const bf16x8*)&Ksm[kk * 16 + lr][lg * 8];
            bf16x8 k1 = *(const bf16x8*)&Ksm[kk * 16 + lr][32 + lg * 8];
            f32x4 z = {};
            z = mfma16(qf0, k0, z);
            z = mfma16(qf1, k1, z);
            s[kk] = z;
        }
        // scale + causal mask
#pragma unroll
        for (int kk = 0; kk < 2; ++kk)
#pragma unroll
            for (int e = 0; e < 4; ++e) {
                int key = kt * 32 + kk * 16 + lr;
                int qi  = qbase + lg * 4 + e;
                float v = s[kk][e] * 0.125f;
                s[kk][e] = (key <= qi) ? v : -1e30f;
            }
        // online softmax
        float mn[4], alpha[4];
#pragma unroll
        for (int e = 0; e < 4; ++e) {
            float v = fmaxf(s[0][e], s[1][e]);
            v = fmaxf(v, __shfl_xor(v, 1));
            v = fmaxf(v, __shfl_xor(v, 2));
            v = fmaxf(v, __shfl_xor(v, 4));
            v = fmaxf(v, __shfl_xor(v, 8));
            mn[e]    = fmaxf(m_run[e], v);
            alpha[e] = __expf(m_run[e] - mn[e]);
            m_run[e] = mn[e];
        }
#pragma unroll
        for (int e = 0; e < 4; ++e) {
            float p0 = __expf(s[0][e] - mn[e]);
            float p1 = __expf(s[1][e] - mn[e]);
            Psm[wave][lg * 4 + e][lr]      = (bf16_t)p0;
            Psm[wave][lg * 4 + e][16 + lr] = (bf16_t)p1;
            float sm2 = p0 + p1;
            sm2 += __shfl_xor(sm2, 1);
            sm2 += __shfl_xor(sm2, 2);
            sm2 += __shfl_xor(sm2, 4);
            sm2 += __shfl_xor(sm2, 8);
            l_run[e] = l_run[e] * alpha[e] + sm2;
        }
#pragma unroll
        for (int d = 0; d < 4; ++d)
#pragma unroll
            for (int e = 0; e < 4; ++e) o[d][e] *= alpha[e];

        // P round-trip through per-wave LDS (same-wave ordering fence)
        asm volatile("s_waitcnt lgkmcnt(0)" ::: "memory");
        bf16x8 pf = *(const bf16x8*)&Psm[wave][lr][lg * 8];
#pragma unroll
        for (int db = 0; db < 4; ++db) {
            bf16x8 vf = *(const bf16x8*)&Vsm[db * 16 + lr][lg * 8];
            o[db] = mfma16(pf, vf, o[db]);
        }
    }

    // write O / l
#pragma unroll
    for (int e = 0; e < 4; ++e) {
        float inv = 1.0f / l_run[e];
        bf16_t* orow = Ob + base + (size_t)(qbase + lg * 4 + e) * C_DIM;
#pragma unroll
        for (int db = 0; db < 4; ++db)
            orow[db * 16 + lr] = (bf16_t)(o[db][e] * inv);
    }
}

// ---------------------------------------------------------------------------
// Host launcher
// ---------------------------------------------------------------------------
extern "C" void kernel_launch(void* const* d_in, const int* in_sizes, int n_in,
                              void* d_out, int out_size, void* d_ws, size_t ws_size,
                              hipStream_t stream) {
    const int*   x      = (const int*)d_in[0];
    const float* tok    = (const float*)d_in[1];
    const float* pos    = (const float*)d_in[2];
    const float* Wq     = (const float*)d_in[3];
    const float* Wk     = (const float*)d_in[4];
    const float* Wv     = (const float*)d_in[5];
    const float* Wproj  = (const float*)d_in[6];
    const float* bproj  = (const float*)d_in[7];
    const float* ln1_g  = (const float*)d_in[8];
    const float* ln1_b  = (const float*)d_in[9];
    const float* ln2_g  = (const float*)d_in[10];
    const float* ln2_b  = (const float*)d_in[11];
    const float* W1     = (const float*)d_in[12];
    const float* b1     = (const float*)d_in[13];
    const float* W2     = (const float*)d_in[14];
    const float* b2     = (const float*)d_in[15];
    const float* lnf_g  = (const float*)d_in[16];
    const float* lnf_b  = (const float*)d_in[17];
    const float* Whead  = (const float*)d_in[18];
    float* out = (float*)d_out;

    char* ws = (char*)d_ws;
    float*  h   = (float*)ws;               ws += (size_t)NROWS * C_DIM * 4;
    bf16_t* xn  = (bf16_t*)ws;              ws += (size_t)NROWS * C_DIM * 2;
    bf16_t* qb  = (bf16_t*)ws;              ws += (size_t)NROWS * C_DIM * 2;
    bf16_t* kb  = (bf16_t*)ws;              ws += (size_t)NROWS * C_DIM * 2;
    bf16_t* vb  = (bf16_t*)ws;              ws += (size_t)NROWS * C_DIM * 2;
    bf16_t* ob  = (bf16_t*)ws;              ws += (size_t)NROWS * C_DIM * 2;
    bf16_t* mid = (bf16_t*)ws;              ws += (size_t)NROWS * 4 * C_DIM * 2;

    dim3 blk(256);

    embed_kernel<<<dim3(NROWS * C_DIM / 1024), blk, 0, stream>>>(x, tok, pos, h);

    for (int l = 0; l < L_DIM; ++l) {
        const size_t wo  = (size_t)l * C_DIM * C_DIM;
        const size_t wo1 = (size_t)l * C_DIM * 4 * C_DIM;

        ln_kernel<<<dim3(NROWS / 4), blk, 0, stream>>>(h, ln1_g + l * C_DIM, ln1_b + l * C_DIM, xn);

        gemm_kernel<0><<<dim3(32 * 8), blk, 0, stream>>>(xn, Wq + wo, nullptr, qb, NROWS, C_DIM, C_DIM);
        gemm_kernel<0><<<dim3(32 * 8), blk, 0, stream>>>(xn, Wk + wo, nullptr, kb, NROWS, C_DIM, C_DIM);
        gemm_kernel<0><<<dim3(32 * 8), blk, 0, stream>>>(xn, Wv + wo, nullptr, vb, NROWS, C_DIM, C_DIM);

        attn_kernel<<<dim3(B_DIM * NHEAD * (T_DIM / 64)), blk, 0, stream>>>(qb, kb, vb, ob);

        gemm_kernel<2><<<dim3(32 * 8), blk, 0, stream>>>(ob, Wproj + wo, bproj + l * C_DIM, h, NROWS, C_DIM, C_DIM);

        ln_kernel<<<dim3(NROWS / 4), blk, 0, stream>>>(h, ln2_g + l * C_DIM, ln2_b + l * C_DIM, xn);

        gemm_kernel<1><<<dim3(32 * 32), blk, 0, stream>>>(xn, W1 + wo1, b1 + (size_t)l * 4 * C_DIM, mid, NROWS, 4 * C_DIM, C_DIM);
        gemm_kernel<2><<<dim3(32 * 8), blk, 0, stream>>>(mid, W2 + wo1, b2 + l * C_DIM, h, NROWS, C_DIM, 4 * C_DIM);
    }

    ln_kernel<<<dim3(NROWS / 4), blk, 0, stream>>>(h, lnf_g, lnf_b, xn);
    gemm_kernel<3><<<dim3(32 * 250), blk, 0, stream>>>(xn, Whead, nullptr, out, NROWS, V_DIM, C_DIM);
}

// Round 2
// 3366.998 us; speedup vs baseline: 1.1971x; 1.1971x over previous
//
#include <hip/hip_runtime.h>
#include <stdint.h>
#include <stddef.h>

#define C_DIM 1024
#define T_DIM 1024
#define B_DIM 4
#define L_DIM 8
#define V_DIM 32000
#define HS 64
#define NHEAD 16
#define NROWS (B_DIM * T_DIM)   // 4096
#define LDQ   3072              // packed qkv row stride

typedef __bf16 bf16_t;
typedef __attribute__((ext_vector_type(8))) __bf16 bf16x8;
typedef __attribute__((ext_vector_type(4))) __bf16 bf16x4;
typedef __attribute__((ext_vector_type(4))) float f32x4;
typedef unsigned int u32;

static __device__ __forceinline__ f32x4 mfma16(bf16x8 a, bf16x8 b, f32x4 c) {
    return __builtin_amdgcn_mfma_f32_16x16x32_bf16(a, b, c, 0, 0, 0);
}

// async global->LDS, 16B per lane. LDS dest must be wave-uniform.
static __device__ __forceinline__ void gl_lds16(const bf16_t* g, bf16_t* l) {
    __builtin_amdgcn_global_load_lds(
        (const __attribute__((address_space(1))) u32*)(const void*)g,
        (__attribute__((address_space(3))) u32*)(void*)l, 16, 0, 0);
}

// ---------------------------------------------------------------------------
// Embedding: h[row][c] = tok_emb[x[row]][c] + pos_emb[row % T][c]   (fp32)
// ---------------------------------------------------------------------------
__global__ __launch_bounds__(256) void embed_kernel(
    const int* __restrict__ x, const float* __restrict__ tok,
    const float* __restrict__ pos, float* __restrict__ h) {
    int idx = blockIdx.x * 256 + threadIdx.x;
    int row = idx >> 8;
    int c4  = (idx & 255) * 4;
    int t   = row & (T_DIM - 1);
    int tk  = x[row];
    float4 a = *(const float4*)(tok + (size_t)tk * C_DIM + c4);
    float4 p = *(const float4*)(pos + (size_t)t * C_DIM + c4);
    float4 r;
    r.x = a.x + p.x; r.y = a.y + p.y; r.z = a.z + p.z; r.w = a.w + p.w;
    *(float4*)(h + (size_t)row * C_DIM + c4) = r;
}

// ---------------------------------------------------------------------------
// Weight convert+transpose:  in f32 [K][N]  ->  out bf16 [N][K]
// grid = (N/64, K/64), 256 threads.
// ---------------------------------------------------------------------------
__global__ __launch_bounds__(256) void wtr_kernel(
    const float* __restrict__ in, bf16_t* __restrict__ out, int K, int N) {
    __shared__ float t[64][65];
    int n0 = blockIdx.x * 64, k0 = blockIdx.y * 64;
    int tx = threadIdx.x & 63, tw = threadIdx.x >> 6;
#pragma unroll 4
    for (int i = 0; i < 16; ++i) {
        int k = tw * 16 + i;
        t[k][tx] = in[(size_t)(k0 + k) * N + n0 + tx];
    }
    __syncthreads();
#pragma unroll 4
    for (int i = 0; i < 16; ++i) {
        int n = tw * 16 + i;
        out[(size_t)(n0 + n) * K + k0 + tx] = (bf16_t)t[tx][n];
    }
}

// ---------------------------------------------------------------------------
// LayerNorm fp32 -> bf16.  One wave per row.
// ---------------------------------------------------------------------------
__global__ __launch_bounds__(256) void ln_kernel(
    const float* __restrict__ x, const float* __restrict__ gam,
    const float* __restrict__ bet, bf16_t* __restrict__ out) {
    int wave = threadIdx.x >> 6, lane = threadIdx.x & 63;
    int row  = blockIdx.x * 4 + wave;
    const float* xr = x + (size_t)row * C_DIM;
    float4 v[4];
    float s = 0.f, sq = 0.f;
#pragma unroll
    for (int i = 0; i < 4; ++i) {
        v[i] = *(const float4*)(xr + i * 256 + lane * 4);
        s  += v[i].x + v[i].y + v[i].z + v[i].w;
        sq += v[i].x * v[i].x + v[i].y * v[i].y + v[i].z * v[i].z + v[i].w * v[i].w;
    }
#pragma unroll
    for (int m = 1; m < 64; m <<= 1) {
        s  += __shfl_xor(s, m);
        sq += __shfl_xor(sq, m);
    }
    float mu  = s * (1.f / 1024.f);
    float var = sq * (1.f / 1024.f) - mu * mu;
    float rs  = rsqrtf(var + 1e-5f);
    bf16_t* orow = out + (size_t)row * C_DIM;
#pragma unroll
    for (int i = 0; i < 4; ++i) {
        int c = i * 256 + lane * 4;
        float4 g4 = *(const float4*)(gam + c);
        float4 b4 = *(const float4*)(bet + c);
        bf16x4 o;
        o[0] = (bf16_t)((v[i].x - mu) * rs * g4.x + b4.x);
        o[1] = (bf16_t)((v[i].y - mu) * rs * g4.y + b4.y);
        o[2] = (bf16_t)((v[i].z - mu) * rs * g4.z + b4.z);
        o[3] = (bf16_t)((v[i].w - mu) * rs * g4.w + b4.w);
        *(bf16x4*)(orow + c) = o;
    }
}

// ---------------------------------------------------------------------------
// GEMM (m97 structure): C[M,N] = A_bf16[M,K] @ Bt_bf16[N,K]^T (+bias)
// MODE 0: store bf16   1: store bf16 relu(+bias)   2: f32 += (+bias)   3: store f32
// 128x128 tile, BK=32, 256 threads (2x2 waves), double-buffered LDS,
// global_load_lds width-16 staging for both operands.
// ---------------------------------------------------------------------------
template <int MODE>
__global__ __launch_bounds__(256) void gemm_kernel(
    const bf16_t* __restrict__ A, const bf16_t* __restrict__ Bt,
    const float* __restrict__ bias, void* __restrict__ Cout,
    int M, int N, int K) {
    __shared__ bf16_t Asm[2][128 * 32];
    __shared__ bf16_t Bsm[2][128 * 32];

    const int tid  = threadIdx.x;
    const int nwg  = gridDim.x;
    int bid = blockIdx.x;
    if ((nwg & 7) == 0) {                 // XCD-aware swizzle (bijective: nwg%8==0)
        int cpx = nwg >> 3;
        bid = (bid & 7) * cpx + (bid >> 3);
    }
    const int MT = M >> 7;
    const int mt = bid % MT, nt = bid / MT;
    const int mbase = mt << 7, nbase = nt << 7;
    const int wave = tid >> 6, lane = tid & 63;
    const int lr = lane & 15, lg = lane >> 4;
    const int wm = wave >> 1, wn = wave & 1;
    const int NK = K >> 5;

    // staging geometry: wave w covers tile rows [w*32, w*32+32) as two 1KB chunks
    const int srow = lane >> 2;           // 0..15
    const int scol = (lane & 3) * 8;      // k elems within 32
    const bf16_t* aRow = A  + (size_t)(mbase + wave * 32 + srow) * K + scol;
    const bf16_t* bRow = Bt + (size_t)(nbase + wave * 32 + srow) * K + scol;
    const int ldsW = wave * 1024;         // wave-uniform LDS elem offset

#define STAGE(buf, kt)                                                        \
    do {                                                                      \
        const bf16_t* ag = aRow + (size_t)(kt) * 32;                          \
        const bf16_t* bg = bRow + (size_t)(kt) * 32;                          \
        gl_lds16(ag,            &Asm[buf][ldsW]);                             \
        gl_lds16(ag + 16 * K,   &Asm[buf][ldsW + 512]);                       \
        gl_lds16(bg,            &Bsm[buf][ldsW]);                             \
        gl_lds16(bg + 16 * K,   &Bsm[buf][ldsW + 512]);                       \
    } while (0)

    STAGE(0, 0);
    __syncthreads();                      // drains vmcnt(0): buf0 ready

    f32x4 acc[4][4] = {};
    int buf = 0;
    for (int kt = 0; kt < NK; ++kt) {
        if (kt + 1 < NK) STAGE(buf ^ 1, kt + 1);
        bf16x8 af[4], bfr[4];
#pragma unroll
        for (int i = 0; i < 4; ++i)
            af[i] = *(const bf16x8*)&Asm[buf][(wm * 64 + i * 16 + lr) * 32 + lg * 8];
#pragma unroll
        for (int j = 0; j < 4; ++j)
            bfr[j] = *(const bf16x8*)&Bsm[buf][(wn * 64 + j * 16 + lr) * 32 + lg * 8];
#pragma unroll
        for (int i = 0; i < 4; ++i)
#pragma unroll
            for (int j = 0; j < 4; ++j)
                acc[i][j] = mfma16(af[i], bfr[j], acc[i][j]);
        __syncthreads();                  // next buf ready; cur buf free
        buf ^= 1;
    }
#undef STAGE

    // epilogue: D col = lane&15, row = 4*(lane>>4)+e
    float bj[4];
#pragma unroll
    for (int j = 0; j < 4; ++j)
        bj[j] = bias ? bias[nbase + wn * 64 + j * 16 + lr] : 0.0f;
#pragma unroll
    for (int i = 0; i < 4; ++i) {
#pragma unroll
        for (int j = 0; j < 4; ++j) {
            int col = nbase + wn * 64 + j * 16 + lr;
#pragma unroll
            for (int e = 0; e < 4; ++e) {
                int row = mbase + wm * 64 + i * 16 + lg * 4 + e;
                float val = acc[i][j][e] + bj[j];
                size_t off = (size_t)row * N + col;
                if (MODE == 0) {
                    ((bf16_t*)Cout)[off] = (bf16_t)val;
                } else if (MODE == 1) {
                    ((bf16_t*)Cout)[off] = (bf16_t)fmaxf(val, 0.0f);
                } else if (MODE == 2) {
                    ((float*)Cout)[off] += val;
                } else {
                    ((float*)Cout)[off] = val;
                }
            }
        }
    }
}

// ---------------------------------------------------------------------------
// Flash attention (causal).  Block = (b, h, 64-row q tile), 4 waves x 16 rows.
// q,k,v packed: row stride LDQ.  O row stride C_DIM.
// ---------------------------------------------------------------------------
__global__ __launch_bounds__(256) void attn_kernel(
    const bf16_t* __restrict__ Qb, const bf16_t* __restrict__ Kb,
    const bf16_t* __restrict__ Vb, bf16_t* __restrict__ Ob) {
    __shared__ bf16_t Ksm[32][72];
    __shared__ bf16_t Vsm[64][40];
    __shared__ bf16_t Psm[4][16][40];

    const int tid  = threadIdx.x;
    const int bid  = blockIdx.x;
    const int qt   = bid & 15;
    const int hh   = (bid >> 4) & 15;
    const int bb   = bid >> 8;
    const int wave = tid >> 6, lane = tid & 63;
    const int lr = lane & 15, lg = lane >> 4;
    const int qbase = qt * 64 + wave * 16;
    const size_t basei = ((size_t)bb * T_DIM) * LDQ + hh * HS;
    const size_t baseo = ((size_t)bb * T_DIM) * C_DIM + hh * HS;

    const bf16_t* qrow = Qb + basei + (size_t)(qbase + lr) * LDQ;
    bf16x8 qf0 = *(const bf16x8*)(qrow + lg * 8);
    bf16x8 qf1 = *(const bf16x8*)(qrow + 32 + lg * 8);

    f32x4 o[4] = {};
    float m_run[4], l_run[4];
#pragma unroll
    for (int e = 0; e < 4; ++e) { m_run[e] = -1e30f; l_run[e] = 0.f; }

    const int skey = tid >> 3, sch = tid & 7;
    const bf16_t* kst = Kb + basei + (size_t)skey * LDQ + sch * 8;
    const bf16_t* vst = Vb + basei + (size_t)skey * LDQ + sch * 8;

    const int nkt = 2 * qt + 2;
    for (int kt = 0; kt < nkt; ++kt) {
        __syncthreads();
        uint4 kv = *(const uint4*)(kst + (size_t)kt * 32 * LDQ);
        uint4 vv = *(const uint4*)(vst + (size_t)kt * 32 * LDQ);
        *(uint4*)&Ksm[skey][sch * 8] = kv;
        const bf16_t* ve = (const bf16_t*)&vv;
#pragma unroll
        for (int j = 0; j < 8; ++j) Vsm[sch * 8 + j][skey] = ve[j];
        __syncthreads();

        f32x4 s[2];
#pragma unroll
        for (int kk = 0; kk < 2; ++kk) {
            bf16x8 k0 = *(const bf16x8*)&Ksm[kk * 16 + lr][lg * 8];
            bf16x8 k1 = *(const bf16x8*)&Ksm[kk * 16 + lr][32 + lg * 8];
            f32x4 z = {};
            z = mfma16(qf0, k0, z);
            z = mfma16(qf1, k1, z);
            s[kk] = z;
        }
#pragma unroll
        for (int kk = 0; kk < 2; ++kk)
#pragma unroll
            for (int e = 0; e < 4; ++e) {
                int key = kt * 32 + kk * 16 + lr;
                int qi  = qbase + lg * 4 + e;
                float v = s[kk][e] * 0.125f;
                s[kk][e] = (key <= qi) ? v : -1e30f;
            }
        float mn[4], alpha[4];
#pragma unroll
        for (int e = 0; e < 4; ++e) {
            float v = fmaxf(s[0][e], s[1][e]);
            v = fmaxf(v, __shfl_xor(v, 1));
            v = fmaxf(v, __shfl_xor(v, 2));
            v = fmaxf(v, __shfl_xor(v, 4));
            v = fmaxf(v, __shfl_xor(v, 8));
            mn[e]    = fmaxf(m_run[e], v);
            alpha[e] = __expf(m_run[e] - mn[e]);
            m_run[e] = mn[e];
        }
#pragma unroll
        for (int e = 0; e < 4; ++e) {
            float p0 = __expf(s[0][e] - mn[e]);
            float p1 = __expf(s[1][e] - mn[e]);
            Psm[wave][lg * 4 + e][lr]      = (bf16_t)p0;
            Psm[wave][lg * 4 + e][16 + lr] = (bf16_t)p1;
            float sm2 = p0 + p1;
            sm2 += __shfl_xor(sm2, 1);
            sm2 += __shfl_xor(sm2, 2);
            sm2 += __shfl_xor(sm2, 4);
            sm2 += __shfl_xor(sm2, 8);
            l_run[e] = l_run[e] * alpha[e] + sm2;
        }
#pragma unroll
        for (int d = 0; d < 4; ++d)
#pragma unroll
            for (int e = 0; e < 4; ++e) o[d][e] *= alpha[e];

        asm volatile("s_waitcnt lgkmcnt(0)" ::: "memory");
        bf16x8 pf = *(const bf16x8*)&Psm[wave][lr][lg * 8];
#pragma unroll
        for (int db = 0; db < 4; ++db) {
            bf16x8 vf = *(const bf16x8*)&Vsm[db * 16 + lr][lg * 8];
            o[db] = mfma16(pf, vf, o[db]);
        }
    }

#pragma unroll
    for (int e = 0; e < 4; ++e) {
        float inv = 1.0f / l_run[e];
        bf16_t* orow = Ob + baseo + (size_t)(qbase + lg * 4 + e) * C_DIM;
#pragma unroll
        for (int db = 0; db < 4; ++db)
            orow[db * 16 + lr] = (bf16_t)(o[db][e] * inv);
    }
}

// ---------------------------------------------------------------------------
// Host launcher
// ---------------------------------------------------------------------------
extern "C" void kernel_launch(void* const* d_in, const int* in_sizes, int n_in,
                              void* d_out, int out_size, void* d_ws, size_t ws_size,
                              hipStream_t stream) {
    const int*   x      = (const int*)d_in[0];
    const float* tok    = (const float*)d_in[1];
    const float* pos    = (const float*)d_in[2];
    const float* Wq     = (const float*)d_in[3];
    const float* Wk     = (const float*)d_in[4];
    const float* Wv     = (const float*)d_in[5];
    const float* Wproj  = (const float*)d_in[6];
    const float* bproj  = (const float*)d_in[7];
    const float* ln1_g  = (const float*)d_in[8];
    const float* ln1_b  = (const float*)d_in[9];
    const float* ln2_g  = (const float*)d_in[10];
    const float* ln2_b  = (const float*)d_in[11];
    const float* W1     = (const float*)d_in[12];
    const float* b1     = (const float*)d_in[13];
    const float* W2     = (const float*)d_in[14];
    const float* b2     = (const float*)d_in[15];
    const float* lnf_g  = (const float*)d_in[16];
    const float* lnf_b  = (const float*)d_in[17];
    const float* Whead  = (const float*)d_in[18];
    float* out = (float*)d_out;

    char* ws = (char*)d_ws;
    float*  h    = (float*)ws;   ws += (size_t)NROWS * C_DIM * 4;          // 16 MB
    bf16_t* xn   = (bf16_t*)ws;  ws += (size_t)NROWS * C_DIM * 2;          // 8 MB
    bf16_t* qkvb = (bf16_t*)ws;  ws += (size_t)NROWS * LDQ * 2;            // 24 MB
    bf16_t* ob   = (bf16_t*)ws;  ws += (size_t)NROWS * C_DIM * 2;          // 8 MB
    bf16_t* mid  = (bf16_t*)ws;  ws += (size_t)NROWS * 4 * C_DIM * 2;      // 32 MB
    bf16_t* wT   = (bf16_t*)ws;  ws += (size_t)V_DIM * C_DIM * 2;          // 65.5 MB

    const size_t M1 = (size_t)C_DIM * C_DIM;       // 1M params
    bf16_t* qkvT  = wT;                            // [3072][1024]
    bf16_t* projT = wT + 3 * M1;                   // [1024][1024]
    bf16_t* w1T   = wT + 4 * M1;                   // [4096][1024]
    bf16_t* w2T   = wT + 8 * M1;                   // [1024][4096]

    dim3 blk(256);

    embed_kernel<<<dim3(NROWS * C_DIM / 1024), blk, 0, stream>>>(x, tok, pos, h);

    for (int l = 0; l < L_DIM; ++l) {
        const size_t wo  = (size_t)l * M1;
        const size_t wo1 = (size_t)l * 4 * M1;

        // weight convert+transpose for this layer (reused buffer)
        wtr_kernel<<<dim3(16, 16), blk, 0, stream>>>(Wq + wo,    qkvT,           C_DIM, C_DIM);
        wtr_kernel<<<dim3(16, 16), blk, 0, stream>>>(Wk + wo,    qkvT + M1,      C_DIM, C_DIM);
        wtr_kernel<<<dim3(16, 16), blk, 0, stream>>>(Wv + wo,    qkvT + 2 * M1,  C_DIM, C_DIM);
        wtr_kernel<<<dim3(16, 16), blk, 0, stream>>>(Wproj + wo, projT,          C_DIM, C_DIM);
        wtr_kernel<<<dim3(64, 16), blk, 0, stream>>>(W1 + wo1,   w1T,            C_DIM, 4 * C_DIM);
        wtr_kernel<<<dim3(16, 64), blk, 0, stream>>>(W2 + wo1,   w2T,            4 * C_DIM, C_DIM);

        ln_kernel<<<dim3(NROWS / 4), blk, 0, stream>>>(h, ln1_g + l * C_DIM, ln1_b + l * C_DIM, xn);

        // fused QKV: N = 3072
        gemm_kernel<0><<<dim3(32 * 24), blk, 0, stream>>>(xn, qkvT, nullptr, qkvb, NROWS, LDQ, C_DIM);

        attn_kernel<<<dim3(B_DIM * NHEAD * (T_DIM / 64)), blk, 0, stream>>>(
            qkvb, qkvb + C_DIM, qkvb + 2 * C_DIM, ob);

        gemm_kernel<2><<<dim3(32 * 8), blk, 0, stream>>>(ob, projT, bproj + l * C_DIM, h, NROWS, C_DIM, C_DIM);

        ln_kernel<<<dim3(NROWS / 4), blk, 0, stream>>>(h, ln2_g + l * C_DIM, ln2_b + l * C_DIM, xn);

        gemm_kernel<1><<<dim3(32 * 32), blk, 0, stream>>>(xn, w1T, b1 + (size_t)l * 4 * C_DIM, mid, NROWS, 4 * C_DIM, C_DIM);
        gemm_kernel<2><<<dim3(32 * 8), blk, 0, stream>>>(mid, w2T, b2 + l * C_DIM, h, NROWS, C_DIM, 4 * C_DIM);
    }

    ln_kernel<<<dim3(NROWS / 4), blk, 0, stream>>>(h, lnf_g, lnf_b, xn);
    wtr_kernel<<<dim3(500, 16), blk, 0, stream>>>(Whead, wT, C_DIM, V_DIM);
    gemm_kernel<3><<<dim3(32 * 250), blk, 0, stream>>>(xn, wT, nullptr, out, NROWS, V_DIM, C_DIM);
}

// Round 3
// 2826.526 us; speedup vs baseline: 1.4260x; 1.1912x over previous
//
#include <hip/hip_runtime.h>
#include <stdint.h>
#include <stddef.h>

#define C_DIM 1024
#define T_DIM 1024
#define B_DIM 4
#define L_DIM 8
#define V_DIM 32000
#define HS 64
#define NHEAD 16
#define NROWS (B_DIM * T_DIM)   // 4096
#define LDQ   3072              // packed qkv row stride

typedef __bf16 bf16_t;
typedef __attribute__((ext_vector_type(8))) __bf16 bf16x8;
typedef __attribute__((ext_vector_type(4))) __bf16 bf16x4;
typedef __attribute__((ext_vector_type(4))) float f32x4;
typedef unsigned int u32;
typedef unsigned short u16;

static __device__ __forceinline__ f32x4 mfma16(bf16x8 a, bf16x8 b, f32x4 c) {
    return __builtin_amdgcn_mfma_f32_16x16x32_bf16(a, b, c, 0, 0, 0);
}

// async global->LDS, 16B per lane. LDS dest must be wave-uniform.
static __device__ __forceinline__ void gl_lds16(const bf16_t* g, bf16_t* l) {
    __builtin_amdgcn_global_load_lds(
        (const __attribute__((address_space(1))) u32*)(const void*)g,
        (__attribute__((address_space(3))) u32*)(void*)l, 16, 0, 0);
}

// ---------------------------------------------------------------------------
// Embedding
// ---------------------------------------------------------------------------
__global__ __launch_bounds__(256) void embed_kernel(
    const int* __restrict__ x, const float* __restrict__ tok,
    const float* __restrict__ pos, float* __restrict__ h) {
    int idx = blockIdx.x * 256 + threadIdx.x;
    int row = idx >> 8;
    int c4  = (idx & 255) * 4;
    int t   = row & (T_DIM - 1);
    int tk  = x[row];
    float4 a = *(const float4*)(tok + (size_t)tk * C_DIM + c4);
    float4 p = *(const float4*)(pos + (size_t)t * C_DIM + c4);
    float4 r;
    r.x = a.x + p.x; r.y = a.y + p.y; r.z = a.z + p.z; r.w = a.w + p.w;
    *(float4*)(h + (size_t)row * C_DIM + c4) = r;
}

// ---------------------------------------------------------------------------
// Weight convert+transpose 64x64 tile body:  f32 [K][N] -> bf16 [N][K]
// ---------------------------------------------------------------------------
static __device__ __forceinline__ void wtr_tile(
    const float* __restrict__ in, bf16_t* __restrict__ out,
    int K, int N, int n0, int k0, int tid) {
    __shared__ float t[64][65];
    int tx = tid & 63, tw = tid >> 6;
#pragma unroll 4
    for (int i = 0; i < 16; ++i) {
        int k = tw * 16 + i;
        t[k][tx] = in[(size_t)(k0 + k) * N + n0 + tx];
    }
    __syncthreads();
#pragma unroll 4
    for (int i = 0; i < 16; ++i) {
        int n = tw * 16 + i;
        out[(size_t)(n0 + n) * K + k0 + tx] = (bf16_t)t[tx][n];
    }
}

__global__ __launch_bounds__(256) void wtr_kernel(
    const float* __restrict__ in, bf16_t* __restrict__ out, int K, int N) {
    wtr_tile(in, out, K, N, blockIdx.x * 64, blockIdx.y * 64, threadIdx.x);
}

// All 6 per-layer weight matrices in one launch (3072 blocks).
__global__ __launch_bounds__(256) void wtr_layer_kernel(
    const float* __restrict__ Wq, const float* __restrict__ Wk,
    const float* __restrict__ Wv, const float* __restrict__ Wp,
    const float* __restrict__ W1, const float* __restrict__ W2,
    bf16_t* __restrict__ qkvT, bf16_t* __restrict__ projT,
    bf16_t* __restrict__ w1T, bf16_t* __restrict__ w2T) {
    int b = blockIdx.x;
    const float* in; bf16_t* out; int K, N, tn, tk;
    if (b < 1024) {
        int which = b >> 8, t = b & 255;
        in  = which == 0 ? Wq : which == 1 ? Wk : which == 2 ? Wv : Wp;
        out = which < 3 ? qkvT + (size_t)which * C_DIM * C_DIM : projT;
        K = C_DIM; N = C_DIM; tn = t & 15; tk = t >> 4;
    } else if (b < 2048) {
        int t = b - 1024; in = W1; out = w1T;
        K = C_DIM; N = 4 * C_DIM; tn = t & 63; tk = t >> 6;
    } else {
        int t = b - 2048; in = W2; out = w2T;
        K = 4 * C_DIM; N = C_DIM; tn = t & 15; tk = t >> 4;
    }
    wtr_tile(in, out, K, N, tn * 64, tk * 64, threadIdx.x);
}

// ---------------------------------------------------------------------------
// LayerNorm fp32 -> bf16.  One wave per row.
// ---------------------------------------------------------------------------
__global__ __launch_bounds__(256) void ln_kernel(
    const float* __restrict__ x, const float* __restrict__ gam,
    const float* __restrict__ bet, bf16_t* __restrict__ out) {
    int wave = threadIdx.x >> 6, lane = threadIdx.x & 63;
    int row  = blockIdx.x * 4 + wave;
    const float* xr = x + (size_t)row * C_DIM;
    float4 v[4];
    float s = 0.f, sq = 0.f;
#pragma unroll
    for (int i = 0; i < 4; ++i) {
        v[i] = *(const float4*)(xr + i * 256 + lane * 4);
        s  += v[i].x + v[i].y + v[i].z + v[i].w;
        sq += v[i].x * v[i].x + v[i].y * v[i].y + v[i].z * v[i].z + v[i].w * v[i].w;
    }
#pragma unroll
    for (int m = 1; m < 64; m <<= 1) {
        s  += __shfl_xor(s, m);
        sq += __shfl_xor(sq, m);
    }
    float mu  = s * (1.f / 1024.f);
    float var = sq * (1.f / 1024.f) - mu * mu;
    float rs  = rsqrtf(var + 1e-5f);
    bf16_t* orow = out + (size_t)row * C_DIM;
#pragma unroll
    for (int i = 0; i < 4; ++i) {
        int c = i * 256 + lane * 4;
        float4 g4 = *(const float4*)(gam + c);
        float4 b4 = *(const float4*)(bet + c);
        bf16x4 o;
        o[0] = (bf16_t)((v[i].x - mu) * rs * g4.x + b4.x);
        o[1] = (bf16_t)((v[i].y - mu) * rs * g4.y + b4.y);
        o[2] = (bf16_t)((v[i].z - mu) * rs * g4.z + b4.z);
        o[3] = (bf16_t)((v[i].w - mu) * rs * g4.w + b4.w);
        *(bf16x4*)(orow + c) = o;
    }
}

// ---------------------------------------------------------------------------
// GEMM (m97 structure + T2 both-sides swizzle): C = A_bf16[M,K] @ Bt[N,K]^T
// MODE 0: store bf16   1: bf16 relu(+bias)   2: f32 += (+bias)   3: store f32
// Swizzle: LDS slot c' holds logical k-chunk c ^ ((row>>1)&3); achieved by
// pre-swizzling the per-lane GLOBAL source (gl_lds dest stays linear).
// ---------------------------------------------------------------------------
template <int MODE>
__global__ __launch_bounds__(256) void gemm_kernel(
    const bf16_t* __restrict__ A, const bf16_t* __restrict__ Bt,
    const float* __restrict__ bias, void* __restrict__ Cout,
    int M, int N, int K) {
    __shared__ bf16_t Asm[2][128 * 32];
    __shared__ bf16_t Bsm[2][128 * 32];

    const int tid  = threadIdx.x;
    const int nwg  = gridDim.x;
    int bid = blockIdx.x;
    if ((nwg & 7) == 0) {
        int cpx = nwg >> 3;
        bid = (bid & 7) * cpx + (bid >> 3);
    }
    const int MT = M >> 7;
    const int mt = bid % MT, nt = bid / MT;
    const int mbase = mt << 7, nbase = nt << 7;
    const int wave = tid >> 6, lane = tid & 63;
    const int lr = lane & 15, lg = lane >> 4;
    const int wm = wave >> 1, wn = wave & 1;
    const int NK = K >> 5;

    const int srow = lane >> 2;                       // 0..15
    const int ssw  = (((lane & 3) ^ ((lane >> 3) & 3)) << 3);  // swizzled k-elem off
    const bf16_t* aRow = A  + (size_t)(mbase + wave * 32 + srow) * K + ssw;
    const bf16_t* bRow = Bt + (size_t)(nbase + wave * 32 + srow) * K + ssw;
    const int ldsW = wave * 1024;

#define STAGE(buf, kt)                                                        \
    do {                                                                      \
        const bf16_t* ag = aRow + (size_t)(kt) * 32;                          \
        const bf16_t* bg = bRow + (size_t)(kt) * 32;                          \
        gl_lds16(ag,            &Asm[buf][ldsW]);                             \
        gl_lds16(ag + 16 * K,   &Asm[buf][ldsW + 512]);                       \
        gl_lds16(bg,            &Bsm[buf][ldsW]);                             \
        gl_lds16(bg + 16 * K,   &Bsm[buf][ldsW + 512]);                       \
    } while (0)

    STAGE(0, 0);
    __syncthreads();

    f32x4 acc[4][4] = {};
    const int rsw = ((lg ^ ((lr >> 1) & 3)) << 3);    // swizzled read k-elem off
    int buf = 0;
    for (int kt = 0; kt < NK; ++kt) {
        if (kt + 1 < NK) STAGE(buf ^ 1, kt + 1);
        bf16x8 af[4], bfr[4];
#pragma unroll
        for (int i = 0; i < 4; ++i)
            af[i] = *(const bf16x8*)&Asm[buf][(wm * 64 + i * 16 + lr) * 32 + rsw];
#pragma unroll
        for (int j = 0; j < 4; ++j)
            bfr[j] = *(const bf16x8*)&Bsm[buf][(wn * 64 + j * 16 + lr) * 32 + rsw];
#pragma unroll
        for (int i = 0; i < 4; ++i)
#pragma unroll
            for (int j = 0; j < 4; ++j)
                acc[i][j] = mfma16(af[i], bfr[j], acc[i][j]);
        __syncthreads();
        buf ^= 1;
    }
#undef STAGE

    float bj[4];
#pragma unroll
    for (int j = 0; j < 4; ++j)
        bj[j] = bias ? bias[nbase + wn * 64 + j * 16 + lr] : 0.0f;
#pragma unroll
    for (int i = 0; i < 4; ++i) {
#pragma unroll
        for (int j = 0; j < 4; ++j) {
            int col = nbase + wn * 64 + j * 16 + lr;
#pragma unroll
            for (int e = 0; e < 4; ++e) {
                int row = mbase + wm * 64 + i * 16 + lg * 4 + e;
                float val = acc[i][j][e] + bj[j];
                size_t off = (size_t)row * N + col;
                if (MODE == 0) {
                    ((bf16_t*)Cout)[off] = (bf16_t)val;
                } else if (MODE == 1) {
                    ((bf16_t*)Cout)[off] = (bf16_t)fmaxf(val, 0.0f);
                } else if (MODE == 2) {
                    ((float*)Cout)[off] += val;
                } else {
                    ((float*)Cout)[off] = val;
                }
            }
        }
    }
}

// ---------------------------------------------------------------------------
// Flash attention (causal).  Block = (b, h, 128-row q tile), 4 waves x 32 q.
// KVBLK=64, double-buffered K/V, async-stage split, 1 barrier per tile.
// q,k,v packed (row stride LDQ); O row stride C_DIM.
// ---------------------------------------------------------------------------
__global__ __launch_bounds__(256) void attn_kernel(
    const bf16_t* __restrict__ Qb, const bf16_t* __restrict__ Kb,
    const bf16_t* __restrict__ Vb, bf16_t* __restrict__ Ob) {
    __shared__ bf16_t Ksm[2][64][72];    // [key][d]
    __shared__ bf16_t Vsm[2][64][72];    // [d][key] (transposed)
    __shared__ bf16_t Psm[4][32][72];    // per-wave P [q][key]

    const int tid  = threadIdx.x;
    const int bid  = blockIdx.x;
    const int qt   = bid & 7;
    const int hh   = (bid >> 3) & 15;
    const int bb   = bid >> 7;
    const int wave = tid >> 6, lane = tid & 63;
    const int lr = lane & 15, lg = lane >> 4;
    const int qbase = qt * 128 + wave * 32;
    const size_t basei = ((size_t)bb * T_DIM) * LDQ + hh * HS;
    const size_t baseo = ((size_t)bb * T_DIM) * C_DIM + hh * HS;

    // Q fragments in registers for the whole kernel
    bf16x8 qf[2][2];
#pragma unroll
    for (int rb = 0; rb < 2; ++rb) {
        const bf16_t* qrow = Qb + basei + (size_t)(qbase + rb * 16 + lr) * LDQ;
        qf[rb][0] = *(const bf16x8*)(qrow + lg * 8);
        qf[rb][1] = *(const bf16x8*)(qrow + 32 + lg * 8);
    }

    f32x4 o[2][4] = {};
    float m_run[2][4], l_run[2][4];
#pragma unroll
    for (int rb = 0; rb < 2; ++rb)
#pragma unroll
        for (int e = 0; e < 4; ++e) { m_run[rb][e] = -1e30f; l_run[rb][e] = 0.f; }

    // staging addressing: K: thread -> (row=tid>>2, chunks tid&3 and +4)
    const int krow = tid >> 2, kc = (tid & 3) * 8;
    const bf16_t* kgp = Kb + basei + (size_t)krow * LDQ + kc;
    // V: thread -> (keys vkg,vkg+1, d-slice vds..vds+7), transposed write
    const int vds = (tid & 7) * 8, vkg = (tid >> 3) * 2;
    const bf16_t* vgp0 = Vb + basei + (size_t)vkg * LDQ + vds;
    const bf16_t* vgp1 = vgp0 + LDQ;

    const int nkt = 2 * qt + 2;

    uint4 k0r, k1r, v0r, v1r;
    // prologue: tile 0 -> buf 0
    k0r = *(const uint4*)(kgp);
    k1r = *(const uint4*)(kgp + 32);
    v0r = *(const uint4*)(vgp0);
    v1r = *(const uint4*)(vgp1);
    *(uint4*)&Ksm[0][krow][kc]      = k0r;
    *(uint4*)&Ksm[0][krow][kc + 32] = k1r;
    {
        const u16* e0 = (const u16*)&v0r;
        const u16* e1 = (const u16*)&v1r;
#pragma unroll
        for (int j = 0; j < 8; ++j)
            *(u32*)&Vsm[0][vds + j][vkg] = (u32)e0[j] | ((u32)e1[j] << 16);
    }
    __syncthreads();

    for (int kt = 0; kt < nkt; ++kt) {
        const int c = kt & 1;
        // T14: issue next tile's global loads before compute
        if (kt + 1 < nkt) {
            const size_t go = (size_t)(kt + 1) * 64 * LDQ;
            k0r = *(const uint4*)(kgp + go);
            k1r = *(const uint4*)(kgp + go + 32);
            v0r = *(const uint4*)(vgp0 + go);
            v1r = *(const uint4*)(vgp1 + go);
        }

        // S = Q @ K^T : 4 key-subtiles x 2 row-blocks
        f32x4 s[2][4];
#pragma unroll
        for (int kk = 0; kk < 4; ++kk) {
            bf16x8 kf0 = *(const bf16x8*)&Ksm[c][kk * 16 + lr][lg * 8];
            bf16x8 kf1 = *(const bf16x8*)&Ksm[c][kk * 16 + lr][32 + lg * 8];
#pragma unroll
            for (int rb = 0; rb < 2; ++rb) {
                f32x4 z = {};
                z = mfma16(qf[rb][0], kf0, z);
                z = mfma16(qf[rb][1], kf1, z);
                s[rb][kk] = z;
            }
        }
        // scale + causal mask (wave-uniform fast path)
        if (kt * 64 + 63 > qbase) {
#pragma unroll
            for (int rb = 0; rb < 2; ++rb)
#pragma unroll
                for (int kk = 0; kk < 4; ++kk)
#pragma unroll
                    for (int e = 0; e < 4; ++e) {
                        int key = kt * 64 + kk * 16 + lr;
                        int qi  = qbase + rb * 16 + lg * 4 + e;
                        float v = s[rb][kk][e] * 0.125f;
                        s[rb][kk][e] = (key <= qi) ? v : -1e30f;
                    }
        } else {
#pragma unroll
            for (int rb = 0; rb < 2; ++rb)
#pragma unroll
                for (int kk = 0; kk < 4; ++kk)
#pragma unroll
                    for (int e = 0; e < 4; ++e)
                        s[rb][kk][e] *= 0.125f;
        }

        // online softmax (rows spread over lr-shuffle groups)
#pragma unroll
        for (int rb = 0; rb < 2; ++rb) {
#pragma unroll
            for (int e = 0; e < 4; ++e) {
                float v = fmaxf(fmaxf(s[rb][0][e], s[rb][1][e]),
                                fmaxf(s[rb][2][e], s[rb][3][e]));
                v = fmaxf(v, __shfl_xor(v, 1));
                v = fmaxf(v, __shfl_xor(v, 2));
                v = fmaxf(v, __shfl_xor(v, 4));
                v = fmaxf(v, __shfl_xor(v, 8));
                float mn    = fmaxf(m_run[rb][e], v);
                float alpha = __expf(m_run[rb][e] - mn);
                m_run[rb][e] = mn;
                float ssum = 0.f;
#pragma unroll
                for (int kk = 0; kk < 4; ++kk) {
                    float p = __expf(s[rb][kk][e] - mn);
                    Psm[wave][rb * 16 + lg * 4 + e][kk * 16 + lr] = (bf16_t)p;
                    ssum += p;
                }
                ssum += __shfl_xor(ssum, 1);
                ssum += __shfl_xor(ssum, 2);
                ssum += __shfl_xor(ssum, 4);
                ssum += __shfl_xor(ssum, 8);
                l_run[rb][e] = l_run[rb][e] * alpha + ssum;
#pragma unroll
                for (int db = 0; db < 4; ++db)
                    o[rb][db][e] *= alpha;
            }
        }

        // P round-trip through per-wave LDS
        asm volatile("s_waitcnt lgkmcnt(0)" ::: "memory");
        bf16x8 pf[2][2];
#pragma unroll
        for (int rb = 0; rb < 2; ++rb)
#pragma unroll
            for (int h2 = 0; h2 < 2; ++h2)
                pf[rb][h2] = *(const bf16x8*)&Psm[wave][rb * 16 + lr][h2 * 32 + lg * 8];
#pragma unroll
        for (int h2 = 0; h2 < 2; ++h2)
#pragma unroll
            for (int db = 0; db < 4; ++db) {
                bf16x8 vf = *(const bf16x8*)&Vsm[c][db * 16 + lr][h2 * 32 + lg * 8];
#pragma unroll
                for (int rb = 0; rb < 2; ++rb)
                    o[rb][db] = mfma16(pf[rb][h2], vf, o[rb][db]);
            }

        // write next tile into the other buffer (loads already in flight)
        if (kt + 1 < nkt) {
            const int w = c ^ 1;
            *(uint4*)&Ksm[w][krow][kc]      = k0r;
            *(uint4*)&Ksm[w][krow][kc + 32] = k1r;
            const u16* e0 = (const u16*)&v0r;
            const u16* e1 = (const u16*)&v1r;
#pragma unroll
            for (int j = 0; j < 8; ++j)
                *(u32*)&Vsm[w][vds + j][vkg] = (u32)e0[j] | ((u32)e1[j] << 16);
        }
        __syncthreads();
    }

    // epilogue
#pragma unroll
    for (int rb = 0; rb < 2; ++rb)
#pragma unroll
        for (int e = 0; e < 4; ++e) {
            float inv = 1.0f / l_run[rb][e];
            bf16_t* orow = Ob + baseo + (size_t)(qbase + rb * 16 + lg * 4 + e) * C_DIM;
#pragma unroll
            for (int db = 0; db < 4; ++db)
                orow[db * 16 + lr] = (bf16_t)(o[rb][db][e] * inv);
        }
}

// ---------------------------------------------------------------------------
// Host launcher
// ---------------------------------------------------------------------------
extern "C" void kernel_launch(void* const* d_in, const int* in_sizes, int n_in,
                              void* d_out, int out_size, void* d_ws, size_t ws_size,
                              hipStream_t stream) {
    const int*   x      = (const int*)d_in[0];
    const float* tok    = (const float*)d_in[1];
    const float* pos    = (const float*)d_in[2];
    const float* Wq     = (const float*)d_in[3];
    const float* Wk     = (const float*)d_in[4];
    const float* Wv     = (const float*)d_in[5];
    const float* Wproj  = (const float*)d_in[6];
    const float* bproj  = (const float*)d_in[7];
    const float* ln1_g  = (const float*)d_in[8];
    const float* ln1_b  = (const float*)d_in[9];
    const float* ln2_g  = (const float*)d_in[10];
    const float* ln2_b  = (const float*)d_in[11];
    const float* W1     = (const float*)d_in[12];
    const float* b1     = (const float*)d_in[13];
    const float* W2     = (const float*)d_in[14];
    const float* b2     = (const float*)d_in[15];
    const float* lnf_g  = (const float*)d_in[16];
    const float* lnf_b  = (const float*)d_in[17];
    const float* Whead  = (const float*)d_in[18];
    float* out = (float*)d_out;

    char* ws = (char*)d_ws;
    float*  h    = (float*)ws;   ws += (size_t)NROWS * C_DIM * 4;          // 16 MB
    bf16_t* xn   = (bf16_t*)ws;  ws += (size_t)NROWS * C_DIM * 2;          // 8 MB
    bf16_t* qkvb = (bf16_t*)ws;  ws += (size_t)NROWS * LDQ * 2;            // 24 MB
    bf16_t* ob   = (bf16_t*)ws;  ws += (size_t)NROWS * C_DIM * 2;          // 8 MB
    bf16_t* mid  = (bf16_t*)ws;  ws += (size_t)NROWS * 4 * C_DIM * 2;      // 32 MB
    bf16_t* wT   = (bf16_t*)ws;  ws += (size_t)V_DIM * C_DIM * 2;          // 65.5 MB

    const size_t M1 = (size_t)C_DIM * C_DIM;
    bf16_t* qkvT  = wT;
    bf16_t* projT = wT + 3 * M1;
    bf16_t* w1T   = wT + 4 * M1;
    bf16_t* w2T   = wT + 8 * M1;

    dim3 blk(256);

    embed_kernel<<<dim3(NROWS * C_DIM / 1024), blk, 0, stream>>>(x, tok, pos, h);

    for (int l = 0; l < L_DIM; ++l) {
        const size_t wo  = (size_t)l * M1;
        const size_t wo1 = (size_t)l * 4 * M1;

        wtr_layer_kernel<<<dim3(3072), blk, 0, stream>>>(
            Wq + wo, Wk + wo, Wv + wo, Wproj + wo, W1 + wo1, W2 + wo1,
            qkvT, projT, w1T, w2T);

        ln_kernel<<<dim3(NROWS / 4), blk, 0, stream>>>(h, ln1_g + l * C_DIM, ln1_b + l * C_DIM, xn);

        gemm_kernel<0><<<dim3(32 * 24), blk, 0, stream>>>(xn, qkvT, nullptr, qkvb, NROWS, LDQ, C_DIM);

        attn_kernel<<<dim3(B_DIM * NHEAD * (T_DIM / 128)), blk, 0, stream>>>(
            qkvb, qkvb + C_DIM, qkvb + 2 * C_DIM, ob);

        gemm_kernel<2><<<dim3(32 * 8), blk, 0, stream>>>(ob, projT, bproj + l * C_DIM, h, NROWS, C_DIM, C_DIM);

        ln_kernel<<<dim3(NROWS / 4), blk, 0, stream>>>(h, ln2_g + l * C_DIM, ln2_b + l * C_DIM, xn);

        gemm_kernel<1><<<dim3(32 * 32), blk, 0, stream>>>(xn, w1T, b1 + (size_t)l * 4 * C_DIM, mid, NROWS, 4 * C_DIM, C_DIM);
        gemm_kernel<2><<<dim3(32 * 8), blk, 0, stream>>>(mid, w2T, b2 + l * C_DIM, h, NROWS, C_DIM, 4 * C_DIM);
    }

    ln_kernel<<<dim3(NROWS / 4), blk, 0, stream>>>(h, lnf_g, lnf_b, xn);
    wtr_kernel<<<dim3(500, 16), blk, 0, stream>>>(Whead, wT, C_DIM, V_DIM);
    gemm_kernel<3><<<dim3(32 * 250), blk, 0, stream>>>(xn, wT, nullptr, out, NROWS, V_DIM, C_DIM);
}